// Round 6
// baseline (166.445 us; speedup 1.0000x reference)
//
#include <hip/hip_runtime.h>
#include <math.h>

// Whiten: per-(b,c) mean/std over 224x224 fp32 slices. B*C = 2048.
// Floor: 411 MB read + 411 MB write @ ~6.3 TB/s ~= 131 us. R1 (register
// staging, 1 block/CU, 8 serial rounds) = 156.6 us; the ~26 us gap is the
// per-round serialization (reads drain -> reduce -> stores -> retire).
//
// R6: persistent software pipeline with THREE half-slice register buffers.
// 256 blocks x 1024 threads, 8 slices/block. Slice = chunk A (6400 float4:
// 6/thread + 1 extra for tid<256) + chunk B (6144 float4: 6/thread).
// Per slice s (P=A(s) acc'ed, Q=B(s) loaded, R=free):
//   [1] issue loads A(s+1) -> R          (reads stream through [2]-[4])
//   [2] finish sums with Q, butterfly, LDS-only barrier, stats(s)
//   [3] store normalized A(s) from P
//   [4] store normalized B(s) from Q
//   [5] issue loads B(s+1) -> P          (WAR on P: cheap counted vmcnt,
//                                         SB stores are younger)
//   [6] pre-accumulate A(s+1) from R
// Buffers: 3 x 7 float4 = 84 data VGPR; cap 128 (launch_bounds 1024,4 ->
// 16 waves/CU -> 1 block/CU). Barrier is raw "s_waitcnt lgkmcnt(0);
// s_barrier" so in-flight prefetch loads are NOT drained (__syncthreads
// would emit vmcnt(0)). wred double-buffered by slice parity -> one barrier
// per slice is race-free. Rotation is a static call sequence (no runtime
// buffer indexing).

namespace {
constexpr int   kHW        = 224 * 224;      // 50176
constexpr int   kHW4       = kHW / 4;        // 12544 float4 / slice
constexpr int   kThreads   = 1024;
constexpr int   kWaves     = kThreads / 64;  // 16
constexpr int   kPerBlock  = 8;
constexpr int   kBlocks    = (64 * 32) / kPerBlock;  // 256
constexpr int   kAFull     = 6;              // chunk A full rows
constexpr int   kAExtraOff = kAFull * kThreads;      // 6144
constexpr int   kAExtraCnt = 256;            // tid<256 hold a 7th float4
constexpr int   kBOff      = 6400;           // chunk B base (float4)
constexpr int   kBFull     = 6;              // chunk B rows (6*1024=6144)
constexpr float kMinDev    = 1.0f / 224.0f;  // 1/sqrt(H*W)

typedef float vfloat4 __attribute__((ext_vector_type(4)));
}

__global__ __launch_bounds__(kThreads, 4)   // cap 128 VGPR, 1 block/CU
void whiten_pipe3(const float* __restrict__ x, float* __restrict__ y) {
    __shared__ float2 wred[2][kWaves];

    const int  tid  = threadIdx.x;
    const int  wid  = tid >> 6;
    const int  lane = tid & 63;
    const bool ea   = (tid < kAExtraCnt);
    const size_t base = (size_t)blockIdx.x * kPerBlock * kHW4;
    const vfloat4* __restrict__ xs = reinterpret_cast<const vfloat4*>(x) + base;
    vfloat4* __restrict__ ys       = reinterpret_cast<vfloat4*>(y) + base;

    vfloat4 b0[7], b1[7], b2[7];

    auto loadA = [&](vfloat4 (&B)[7], int s) {
        const vfloat4* __restrict__ p = xs + (size_t)s * kHW4;
#pragma unroll
        for (int i = 0; i < kAFull; ++i) B[i] = p[i * kThreads + tid];
        if (ea) B[6] = p[kAExtraOff + tid];
    };
    auto loadB = [&](vfloat4 (&B)[7], int s) {
        const vfloat4* __restrict__ p = xs + (size_t)s * kHW4 + kBOff;
#pragma unroll
        for (int i = 0; i < kBFull; ++i) B[i] = p[i * kThreads + tid];
    };
    auto acc1 = [&](const vfloat4& v, float& sum, float& ssq) {
        sum += v.x + v.y + v.z + v.w;
        ssq = fmaf(v.x, v.x, ssq);
        ssq = fmaf(v.y, v.y, ssq);
        ssq = fmaf(v.z, v.z, ssq);
        ssq = fmaf(v.w, v.w, ssq);
    };
    auto accA = [&](vfloat4 (&B)[7], float& sum, float& ssq) {
#pragma unroll
        for (int i = 0; i < kAFull; ++i) acc1(B[i], sum, ssq);
        if (ea) acc1(B[6], sum, ssq);
    };
    auto accB = [&](vfloat4 (&B)[7], float& sum, float& ssq) {
#pragma unroll
        for (int i = 0; i < kBFull; ++i) acc1(B[i], sum, ssq);
    };
    auto norm1 = [&](const vfloat4& v, float mean, float rcp) {
        vfloat4 o;
        o.x = (v.x - mean) * rcp;
        o.y = (v.y - mean) * rcp;
        o.z = (v.z - mean) * rcp;
        o.w = (v.w - mean) * rcp;
        return o;
    };

    // slice s: P = A(s) (already accumulated into sum/ssq), Q = B(s) loaded,
    // R = free. Returns partial sums of A(s+1).
    auto slice = [&](vfloat4 (&P)[7], vfloat4 (&Q)[7], vfloat4 (&R)[7],
                     int s, bool pre, float sum, float ssq) -> float2 {
        if (pre) loadA(R, s + 1);                       // [1]
        accB(Q, sum, ssq);                              // [2] waits Q only
#pragma unroll
        for (int off = 32; off >= 1; off >>= 1) {
            sum += __shfl_down(sum, off, 64);
            ssq += __shfl_down(ssq, off, 64);
        }
        if (lane == 0) wred[s & 1][wid] = make_float2(sum, ssq);
        // LDS-only barrier: keep prefetch loads in flight across it.
        asm volatile("s_waitcnt lgkmcnt(0)\n\ts_barrier" ::: "memory");
        float S = 0.f, SS = 0.f;
#pragma unroll
        for (int i = 0; i < kWaves; ++i) {
            S += wred[s & 1][i].x;
            SS += wred[s & 1][i].y;
        }
        const float mean = S * (1.0f / kHW);
        float var = (SS - S * mean) * (1.0f / (kHW - 1));
        var = fmaxf(var, 0.f);
        const float rcp = 1.0f / fmaxf(sqrtf(var), kMinDev);

        vfloat4* __restrict__ pa = ys + (size_t)s * kHW4;
#pragma unroll
        for (int i = 0; i < kAFull; ++i)                // [3] store A(s)
            pa[i * kThreads + tid] = norm1(P[i], mean, rcp);
        if (ea) pa[kAExtraOff + tid] = norm1(P[6], mean, rcp);
        vfloat4* __restrict__ pb = pa + kBOff;
#pragma unroll
        for (int i = 0; i < kBFull; ++i)                // [4] store B(s)
            pb[i * kThreads + tid] = norm1(Q[i], mean, rcp);

        float ns = 0.f, nq = 0.f;
        if (pre) {
            loadB(P, s + 1);                            // [5] reuse P
            accA(R, ns, nq);                            // [6] A(s+1) partials
        }
        return make_float2(ns, nq);
    };

    // prologue
    loadA(b0, 0);
    loadB(b1, 0);
    float sum = 0.f, ssq = 0.f;
    accA(b0, sum, ssq);

    // static 3-buffer rotation over 8 slices: (P,Q,R) <- (R,P,Q)
    float2 c;
    c = slice(b0, b1, b2, 0, true, sum, ssq);
    c = slice(b2, b0, b1, 1, true, c.x, c.y);
    c = slice(b1, b2, b0, 2, true, c.x, c.y);
    c = slice(b0, b1, b2, 3, true, c.x, c.y);
    c = slice(b2, b0, b1, 4, true, c.x, c.y);
    c = slice(b1, b2, b0, 5, true, c.x, c.y);
    c = slice(b0, b1, b2, 6, true, c.x, c.y);
    (void)slice(b2, b0, b1, 7, false, c.x, c.y);
}

extern "C" void kernel_launch(void* const* d_in, const int* in_sizes, int n_in,
                              void* d_out, int out_size, void* d_ws, size_t ws_size,
                              hipStream_t stream) {
    (void)in_sizes; (void)n_in; (void)d_ws; (void)ws_size; (void)out_size;
    const float* x = reinterpret_cast<const float*>(d_in[0]);
    float* y = reinterpret_cast<float*>(d_out);
    whiten_pipe3<<<kBlocks, kThreads, 0, stream>>>(x, y);
}

// Round 7
// 166.054 us; speedup vs baseline: 1.0024x; 1.0024x over previous
//
#include <hip/hip_runtime.h>
#include <math.h>

// Whiten: per-(b,c) mean/std over 224x224 fp32 slices. B*C = 2048 slices.
// Floor: 411 MB read + 411 MB write @ ~6.3 TB/s ~= 131 us.
//
// R7: R1's single-read register-staging skeleton, squeezed under the
// 64-VGPR cap so TWO 1024-thread blocks co-reside per CU
// (__launch_bounds__(1024,8) => 8 waves/SIMD => 64-VGPR cap => 2 blocks/CU).
// Co-resident blocks destagger under contention, so one block's read phase
// overlaps the other's reduce/store/retire bubble (R1 at 1 block/CU paid
// ~3.2 us of serial bubble per round x 8 rounds).
// Register budget: 12 float4 staged (48 VGPR) + 2 accumulators + ~10
// addressing/stats => ~60 < 64. The 0.25-row tail (256 float4/slice,
// tid<256) is staged through a 4 KB LDS buffer instead of a 13th float4
// register, written before the single barrier and read back after it.
// Stats: wave butterfly -> 16-entry LDS -> ONE __syncthreads -> every
// thread broadcast-reads the 16 entries (no tid0 serialization, no second
// barrier). All loads are consumed before the barrier so plain
// __syncthreads() drains nothing.

namespace {
constexpr int kHW      = 224 * 224;                 // 50176
constexpr int kHW4     = kHW / 4;                   // 12544 float4 / slice
constexpr int kThreads = 1024;
constexpr int kIt      = 12;                        // float4 in registers
constexpr int kTailOff = kIt * kThreads;            // 12288
constexpr int kTailCnt = kHW4 - kTailOff;           // 256 (tid<256)
constexpr int kSlices  = 64 * 32;                   // 2048
constexpr int kWaves   = kThreads / 64;             // 16
constexpr float kMinDev = 1.0f / 224.0f;            // 1/sqrt(H*W)

typedef float vfloat4 __attribute__((ext_vector_type(4)));
}

__global__ __launch_bounds__(kThreads, 8)   // 64-VGPR cap -> 2 blocks/CU
void whiten_occ2(const float* __restrict__ x, float* __restrict__ y) {
    __shared__ vfloat4 tail[kTailCnt];      // 4 KB staged tail
    __shared__ float2  wred[kWaves];        // per-wave (sum, sumsq)

    const int tid  = threadIdx.x;
    const int wid  = tid >> 6;
    const int lane = tid & 63;
    const size_t base = (size_t)blockIdx.x * kHW4;
    const vfloat4* __restrict__ xs = reinterpret_cast<const vfloat4*>(x) + base;
    vfloat4* __restrict__ ys       = reinterpret_cast<vfloat4*>(y) + base;

    // ---- single read of the slice: 12 float4 to registers ----
    vfloat4 v[kIt];
#pragma unroll
    for (int i = 0; i < kIt; ++i) v[i] = xs[i * kThreads + tid];

    float sum = 0.f, ssq = 0.f;
    // tail (waves 0-3): load, accumulate, park in LDS (frees the register)
    if (tid < kTailCnt) {
        const vfloat4 t = xs[kTailOff + tid];
        sum += t.x + t.y + t.z + t.w;
        ssq = fmaf(t.x, t.x, ssq);
        ssq = fmaf(t.y, t.y, ssq);
        ssq = fmaf(t.z, t.z, ssq);
        ssq = fmaf(t.w, t.w, ssq);
        tail[tid] = t;
    }
#pragma unroll
    for (int i = 0; i < kIt; ++i) {
        sum += v[i].x + v[i].y + v[i].z + v[i].w;
        ssq = fmaf(v[i].x, v[i].x, ssq);
        ssq = fmaf(v[i].y, v[i].y, ssq);
        ssq = fmaf(v[i].z, v[i].z, ssq);
        ssq = fmaf(v[i].w, v[i].w, ssq);
    }

    // ---- wave64 butterfly ----
#pragma unroll
    for (int off = 32; off >= 1; off >>= 1) {
        sum += __shfl_down(sum, off, 64);
        ssq += __shfl_down(ssq, off, 64);
    }
    if (lane == 0) wred[wid] = make_float2(sum, ssq);
    __syncthreads();   // single barrier; no loads in flight here

    // ---- broadcast stats: every thread reduces the 16 entries ----
    float S = 0.f, SS = 0.f;
#pragma unroll
    for (int i = 0; i < kWaves; ++i) { S += wred[i].x; SS += wred[i].y; }
    const float mean = S * (1.0f / kHW);
    float var = (SS - S * mean) * (1.0f / (kHW - 1));
    var = fmaxf(var, 0.f);
    const float rcp = 1.0f / fmaxf(sqrtf(var), kMinDev);

    // ---- normalize + store from registers ----
#pragma unroll
    for (int i = 0; i < kIt; ++i) {
        vfloat4 o;
        o.x = (v[i].x - mean) * rcp;
        o.y = (v[i].y - mean) * rcp;
        o.z = (v[i].z - mean) * rcp;
        o.w = (v[i].w - mean) * rcp;
        ys[i * kThreads + tid] = o;
    }
    // ---- tail from LDS ----
    if (tid < kTailCnt) {
        const vfloat4 t = tail[tid];
        vfloat4 o;
        o.x = (t.x - mean) * rcp;
        o.y = (t.y - mean) * rcp;
        o.z = (t.z - mean) * rcp;
        o.w = (t.w - mean) * rcp;
        ys[kTailOff + tid] = o;
    }
}

extern "C" void kernel_launch(void* const* d_in, const int* in_sizes, int n_in,
                              void* d_out, int out_size, void* d_ws, size_t ws_size,
                              hipStream_t stream) {
    (void)in_sizes; (void)n_in; (void)d_ws; (void)ws_size; (void)out_size;
    const float* x = reinterpret_cast<const float*>(d_in[0]);
    float* y = reinterpret_cast<float*>(d_out);
    whiten_occ2<<<kSlices, kThreads, 0, stream>>>(x, y);
}